// Round 1
// baseline (156.459 us; speedup 1.0000x reference)
//
#include <hip/hip_runtime.h>
#include <hip/hip_bf16.h>

// Problem constants (fixed by the reference)
#define NQS    16384
#define HWPIX  16384      // 128*128
#define MTOT   65536      // B*NQ == B*H*W
#define NHEADS 8
#define NPTS   4

typedef __attribute__((ext_vector_type(8))) __bf16 bf16x8;
typedef __attribute__((ext_vector_type(4))) __bf16 bf16x4;
typedef __attribute__((ext_vector_type(4))) float  f32x4;

// ---------------- weight prep: transpose to [N][K] + bf16 ----------------
__global__ void prep_weights(const float* __restrict__ Woff,
                             const float* __restrict__ Wattn,
                             const float* __restrict__ boff,
                             const float* __restrict__ battn,
                             const float* __restrict__ Wv,
                             const float* __restrict__ Wout,
                             __bf16* __restrict__ W1t,
                             __bf16* __restrict__ Wvt,
                             __bf16* __restrict__ Wot,
                             float* __restrict__ bias1)
{
    int tid = blockIdx.x * blockDim.x + threadIdx.x;
    int stride = gridDim.x * blockDim.x;
    // W1t: [96][256]; rows 0..63 = W_off columns, rows 64..95 = W_attn columns
    for (int i = tid; i < 96 * 256; i += stride) {
        int n = i >> 8, k = i & 255;
        float v = (n < 64) ? Woff[k * 64 + n] : Wattn[k * 32 + (n - 64)];
        W1t[i] = (__bf16)v;
    }
    for (int i = tid; i < 256 * 256; i += stride) {
        int n = i >> 8, k = i & 255;
        Wvt[i] = (__bf16)Wv[k * 256 + n];
        Wot[i] = (__bf16)Wout[k * 256 + n];
    }
    for (int i = tid; i < 96; i += stride)
        bias1[i] = (i < 64) ? boff[i] : battn[i - 64];
}

// ---------------- MFMA GEMM: Out[M,Ntot] = A[M,256] @ Bt[Ntot,256]^T + bias ----
// BM=128 rows/block, 4 waves each owning 32 rows; BN cols (96 or 128).
// A operand lane layout (16x16x32): row = lane&15, k = (lane>>4)*8 + j  (8 contiguous)
// C/D layout: col = lane&15, row = (lane>>4)*4 + reg   [HW-verified per guide]
template<int BN, bool A_F32, bool OUT_BF16>
__global__ __launch_bounds__(256) void gemm_mfma(
    const void* __restrict__ Aptr,
    const __bf16* __restrict__ Bt,      // [Ntot][256] bf16 (pre-transposed)
    const float* __restrict__ bias,     // [Ntot]
    void* __restrict__ Out,
    int Ntot)
{
    constexpr int BM = 128, BK = 32;
    constexpr int LSTR = 40;            // 32 + 8 pad (80B rows -> <=2-way bank alias)
    constexpr int NF = BN / 16;
    __shared__ __bf16 As[BM * LSTR];
    __shared__ __bf16 Bs[BN * LSTR];

    const int tid  = threadIdx.x;
    const int wave = tid >> 6, lane = tid & 63;
    const int r16  = lane & 15, kq = lane >> 4;     // kq in 0..3
    const long mbase = (long)blockIdx.x * BM;
    const int  nbase = blockIdx.y * BN;

    f32x4 acc[2][NF];
#pragma unroll
    for (int m = 0; m < 2; ++m)
#pragma unroll
        for (int n = 0; n < NF; ++n) acc[m][n] = f32x4{0.f, 0.f, 0.f, 0.f};

    for (int kt = 0; kt < 256; kt += BK) {
        __syncthreads();   // protect LDS from previous iteration's readers
        // stage A tile: 128 rows x 32 k  (chunks of 8 elems)
        for (int c = tid; c < BM * 4; c += 256) {
            int row = c >> 2, seg = c & 3;
            if (A_F32) {
                const float* A = (const float*)Aptr;
                const float4* src = (const float4*)(A + (mbase + row) * 256 + kt + seg * 8);
                float4 v0 = src[0], v1 = src[1];
                bf16x8 o;
                o[0] = (__bf16)v0.x; o[1] = (__bf16)v0.y; o[2] = (__bf16)v0.z; o[3] = (__bf16)v0.w;
                o[4] = (__bf16)v1.x; o[5] = (__bf16)v1.y; o[6] = (__bf16)v1.z; o[7] = (__bf16)v1.w;
                *(bf16x8*)&As[row * LSTR + seg * 8] = o;
            } else {
                const __bf16* A = (const __bf16*)Aptr;
                *(bf16x8*)&As[row * LSTR + seg * 8] =
                    *(const bf16x8*)(A + (mbase + row) * 256 + kt + seg * 8);
            }
        }
        // stage B tile: BN rows (= output cols) x 32 k, straight row-major copy
        for (int c = tid; c < BN * 4; c += 256) {
            int row = c >> 2, seg = c & 3;
            *(bf16x8*)&Bs[row * LSTR + seg * 8] =
                *(const bf16x8*)(Bt + (long)(nbase + row) * 256 + kt + seg * 8);
        }
        __syncthreads();

        bf16x8 aF0 = *(const bf16x8*)&As[(wave * 32 + r16) * LSTR + kq * 8];
        bf16x8 aF1 = *(const bf16x8*)&As[(wave * 32 + 16 + r16) * LSTR + kq * 8];
#pragma unroll
        for (int n = 0; n < NF; ++n) {
            bf16x8 bF = *(const bf16x8*)&Bs[(n * 16 + r16) * LSTR + kq * 8];
            acc[0][n] = __builtin_amdgcn_mfma_f32_16x16x32_bf16(aF0, bF, acc[0][n], 0, 0, 0);
            acc[1][n] = __builtin_amdgcn_mfma_f32_16x16x32_bf16(aF1, bF, acc[1][n], 0, 0, 0);
        }
    }

    // epilogue: add bias, store
#pragma unroll
    for (int m = 0; m < 2; ++m) {
        long row0 = mbase + wave * 32 + m * 16 + kq * 4;
#pragma unroll
        for (int n = 0; n < NF; ++n) {
            int col = nbase + n * 16 + r16;
            float bz = bias[col];
#pragma unroll
            for (int r = 0; r < 4; ++r) {
                float v = acc[m][n][r] + bz;
                if (OUT_BF16) ((__bf16*)Out)[(row0 + r) * (long)Ntot + col] = (__bf16)v;
                else          ((float*) Out)[(row0 + r) * (long)Ntot + col] = v;
            }
        }
    }
}

// ---------------- sampling: softmax + bilinear gather + point reduction ------
// One wave per query. lane -> (head h = lane>>3, channel group dg = lane&7),
// each lane produces 4 output channels c = h*32 + dg*4 .. +3.
__global__ __launch_bounds__(256) void sample_kernel(
    const float* __restrict__ P,          // [MTOT][96]: 64 offsets | 32 attn logits
    const float* __restrict__ refp,       // [MTOT][2]
    const __bf16* __restrict__ vproj,     // [B][HW][256], pixel-major channels
    __bf16* __restrict__ out_mid)         // [MTOT][256]
{
    const int q    = blockIdx.x * 4 + (threadIdx.x >> 6);
    const int lane = threadIdx.x & 63;
    const int h = lane >> 3, dg = lane & 7;
    const int b = q >> 14;                 // NQ = 16384
    const float* Pr = P + (long)q * 96;
    const float rx = refp[(long)q * 2 + 0];
    const float ry = refp[(long)q * 2 + 1];

    // softmax over this head's 4 logits (redundant across the 8 lanes of a head)
    float lg0 = Pr[64 + h * 4 + 0], lg1 = Pr[64 + h * 4 + 1];
    float lg2 = Pr[64 + h * 4 + 2], lg3 = Pr[64 + h * 4 + 3];
    float mx = fmaxf(fmaxf(lg0, lg1), fmaxf(lg2, lg3));
    float e0 = __expf(lg0 - mx), e1 = __expf(lg1 - mx);
    float e2 = __expf(lg2 - mx), e3 = __expf(lg3 - mx);
    float inv = 1.f / (e0 + e1 + e2 + e3);
    float at[4] = {e0 * inv, e1 * inv, e2 * inv, e3 * inv};

    const __bf16* vb = vproj + (long)b * HWPIX * 256 + h * 32 + dg * 4;
    float a0 = 0.f, a1 = 0.f, a2 = 0.f, a3 = 0.f;

#pragma unroll
    for (int p = 0; p < 4; ++p) {
        float ox = Pr[h * 8 + p * 2 + 0] * (0.1f / 128.f);
        float oy = Pr[h * 8 + p * 2 + 1] * (0.1f / 128.f);
        float lx = fminf(fmaxf(rx + ox, 0.f), 1.f);
        float ly = fminf(fmaxf(ry + oy, 0.f), 1.f);
        float ixf = lx * 128.f - 0.5f;
        float iyf = ly * 128.f - 0.5f;
        float x0f = floorf(ixf), y0f = floorf(iyf);
        float wx = ixf - x0f,  wy = iyf - y0f;
        int x0 = (int)x0f, y0 = (int)y0f;
        float attn = at[p];
#pragma unroll
        for (int cy = 0; cy < 2; ++cy) {
#pragma unroll
            for (int cx = 0; cx < 2; ++cx) {
                int xc = x0 + cx, yc = y0 + cy;
                if (xc < 0 || xc > 127 || yc < 0 || yc > 127) continue;  // zero-pad
                float w = (cx ? wx : 1.f - wx) * (cy ? wy : 1.f - wy) * attn;
                const bf16x4 v = *(const bf16x4*)(vb + (yc * 128 + xc) * 256);
                a0 += w * (float)v[0];
                a1 += w * (float)v[1];
                a2 += w * (float)v[2];
                a3 += w * (float)v[3];
            }
        }
    }
    bf16x4 o;
    o[0] = (__bf16)a0; o[1] = (__bf16)a1; o[2] = (__bf16)a2; o[3] = (__bf16)a3;
    *(bf16x4*)(out_mid + (long)q * 256 + h * 32 + dg * 4) = o;
}

extern "C" void kernel_launch(void* const* d_in, const int* in_sizes, int n_in,
                              void* d_out, int out_size, void* d_ws, size_t ws_size,
                              hipStream_t stream)
{
    const float* query  = (const float*)d_in[0];
    const float* refp   = (const float*)d_in[1];
    const float* value  = (const float*)d_in[2];
    const float* W_off  = (const float*)d_in[3];
    const float* b_off  = (const float*)d_in[4];
    const float* W_attn = (const float*)d_in[5];
    const float* b_attn = (const float*)d_in[6];
    const float* W_v    = (const float*)d_in[7];
    const float* b_v    = (const float*)d_in[8];
    const float* W_out  = (const float*)d_in[9];
    const float* b_out  = (const float*)d_in[10];

    // workspace carve (~88.3 MB total)
    char* w = (char*)d_ws;
    float*  P       = (float*)w;   w += (size_t)MTOT * 96 * 4;    // 24 MB
    __bf16* vproj   = (__bf16*)w;  w += (size_t)MTOT * 256 * 2;   // 32 MB
    __bf16* out_mid = (__bf16*)w;  w += (size_t)MTOT * 256 * 2;   // 32 MB
    __bf16* W1t     = (__bf16*)w;  w += 96 * 256 * 2;
    __bf16* Wvt     = (__bf16*)w;  w += 256 * 256 * 2;
    __bf16* Wot     = (__bf16*)w;  w += 256 * 256 * 2;
    float*  bias1   = (float*)w;   w += 96 * 4;

    prep_weights<<<120, 256, 0, stream>>>(W_off, W_attn, b_off, b_attn,
                                          W_v, W_out, W1t, Wvt, Wot, bias1);
    // P = query @ [W_off|W_attn] + bias1
    gemm_mfma<96, true, false><<<dim3(MTOT / 128, 1), 256, 0, stream>>>(
        query, W1t, bias1, P, 96);
    // vproj = value @ W_v + b_v   (bf16, pixel-major)
    gemm_mfma<128, true, true><<<dim3(MTOT / 128, 2), 256, 0, stream>>>(
        value, Wvt, b_v, vproj, 256);
    // bilinear sampling + attention reduction
    sample_kernel<<<MTOT / 4, 256, 0, stream>>>(P, refp, vproj, out_mid);
    // out = out_mid @ W_out + b_out  (fp32)
    gemm_mfma<128, false, false><<<dim3(MTOT / 128, 2), 256, 0, stream>>>(
        out_mid, Wot, b_out, d_out, 256);
}

// Round 2
// 134.887 us; speedup vs baseline: 1.1599x; 1.1599x over previous
//
#include <hip/hip_runtime.h>
#include <hip/hip_bf16.h>

// Problem constants (fixed by the reference)
#define NQS    16384
#define HWPIX  16384      // 128*128
#define MTOT   65536      // B*NQ == B*H*W
#define NHEADS 8
#define NPTS   4

typedef __attribute__((ext_vector_type(8))) __bf16 bf16x8;
typedef __attribute__((ext_vector_type(4))) __bf16 bf16x4;
typedef __attribute__((ext_vector_type(4))) float  f32x4;

// ---------------- weight prep: transpose to [N][K] + bf16 ----------------
__global__ void prep_weights(const float* __restrict__ Woff,
                             const float* __restrict__ Wattn,
                             const float* __restrict__ boff,
                             const float* __restrict__ battn,
                             const float* __restrict__ Wv,
                             const float* __restrict__ Wout,
                             __bf16* __restrict__ W1t,
                             __bf16* __restrict__ Wvt,
                             __bf16* __restrict__ Wot,
                             float* __restrict__ bias1)
{
    int tid = blockIdx.x * blockDim.x + threadIdx.x;
    int stride = gridDim.x * blockDim.x;
    // W1t: [96][256]; rows 0..63 = W_off columns, rows 64..95 = W_attn columns
    for (int i = tid; i < 96 * 256; i += stride) {
        int n = i >> 8, k = i & 255;
        float v = (n < 64) ? Woff[k * 64 + n] : Wattn[k * 32 + (n - 64)];
        W1t[i] = (__bf16)v;
    }
    for (int i = tid; i < 256 * 256; i += stride) {
        int n = i >> 8, k = i & 255;
        Wvt[i] = (__bf16)Wv[k * 256 + n];
        Wot[i] = (__bf16)Wout[k * 256 + n];
    }
    for (int i = tid; i < 96; i += stride)
        bias1[i] = (i < 64) ? boff[i] : battn[i - 64];
}

// ---------------- GEMM1: Out[M,96] = A[M,256](f32) @ Bt[96,256]^T + bias ----
// BM=128 rows/block, 4 waves each owning 32 rows (proven structure).
__global__ __launch_bounds__(256) void gemm96(
    const float* __restrict__ A,
    const __bf16* __restrict__ Bt,
    const float* __restrict__ bias,
    float* __restrict__ Out)
{
    constexpr int BM = 128, BK = 32, BN = 96;
    constexpr int LSTR = 40;            // 80-B rows: bank-conflict-free (2-way only)
    constexpr int NF = BN / 16;
    __shared__ __bf16 As[BM * LSTR];
    __shared__ __bf16 Bs[BN * LSTR];

    const int tid  = threadIdx.x;
    const int wave = tid >> 6, lane = tid & 63;
    const int r16  = lane & 15, kq = lane >> 4;
    const long mbase = (long)blockIdx.x * BM;

    f32x4 acc[2][NF];
#pragma unroll
    for (int m = 0; m < 2; ++m)
#pragma unroll
        for (int n = 0; n < NF; ++n) acc[m][n] = f32x4{0.f, 0.f, 0.f, 0.f};

    for (int kt = 0; kt < 256; kt += BK) {
        __syncthreads();
        for (int c = tid; c < BM * 4; c += 256) {
            int row = c >> 2, seg = c & 3;
            const float4* src = (const float4*)(A + (mbase + row) * 256 + kt + seg * 8);
            float4 v0 = src[0], v1 = src[1];
            bf16x8 o;
            o[0] = (__bf16)v0.x; o[1] = (__bf16)v0.y; o[2] = (__bf16)v0.z; o[3] = (__bf16)v0.w;
            o[4] = (__bf16)v1.x; o[5] = (__bf16)v1.y; o[6] = (__bf16)v1.z; o[7] = (__bf16)v1.w;
            *(bf16x8*)&As[row * LSTR + seg * 8] = o;
        }
        for (int c = tid; c < BN * 4; c += 256) {
            int row = c >> 2, seg = c & 3;
            *(bf16x8*)&Bs[row * LSTR + seg * 8] =
                *(const bf16x8*)(Bt + (long)row * 256 + kt + seg * 8);
        }
        __syncthreads();

        bf16x8 aF0 = *(const bf16x8*)&As[(wave * 32 + r16) * LSTR + kq * 8];
        bf16x8 aF1 = *(const bf16x8*)&As[(wave * 32 + 16 + r16) * LSTR + kq * 8];
#pragma unroll
        for (int n = 0; n < NF; ++n) {
            bf16x8 bF = *(const bf16x8*)&Bs[(n * 16 + r16) * LSTR + kq * 8];
            acc[0][n] = __builtin_amdgcn_mfma_f32_16x16x32_bf16(aF0, bF, acc[0][n], 0, 0, 0);
            acc[1][n] = __builtin_amdgcn_mfma_f32_16x16x32_bf16(aF1, bF, acc[1][n], 0, 0, 0);
        }
    }

#pragma unroll
    for (int m = 0; m < 2; ++m) {
        long row0 = mbase + wave * 32 + m * 16 + kq * 4;
#pragma unroll
        for (int n = 0; n < NF; ++n) {
            int col = n * 16 + r16;
            float bz = bias[col];
#pragma unroll
            for (int r = 0; r < 4; ++r)
                Out[(row0 + r) * 96 + col] = acc[m][n][r] + bz;
        }
    }
}

// ---------------- GEMM256: Out[M,256] = A[M,256] @ Bt[256,256]^T + bias ----
// 512 threads / 8 waves; wave w owns rows w*16..+16, all 256 cols.
// Single pass over A (no grid.y) -> A fetched exactly once.
template<bool A_F32, bool OUT_BF16>
__global__ __launch_bounds__(512) void gemm256(
    const void* __restrict__ Aptr,
    const __bf16* __restrict__ Bt,
    const float* __restrict__ bias,
    void* __restrict__ Out)
{
    constexpr int BM = 128, BK = 32;
    constexpr int LSTR = 40;
    __shared__ __bf16 As[BM * LSTR];    // 10.2 KB
    __shared__ __bf16 Bs[256 * LSTR];   // 20.5 KB

    const int tid  = threadIdx.x;
    const int wave = tid >> 6, lane = tid & 63;
    const int r16  = lane & 15, kq = lane >> 4;
    const long mbase = (long)blockIdx.x * BM;

    f32x4 acc[16];
#pragma unroll
    for (int n = 0; n < 16; ++n) acc[n] = f32x4{0.f, 0.f, 0.f, 0.f};

    for (int kt = 0; kt < 256; kt += BK) {
        __syncthreads();
        if (A_F32) {
            // 128 rows x 8 segs of 4 floats = 1024 chunks, 2/thread
            for (int c = tid; c < BM * 8; c += 512) {
                int row = c >> 3, seg = c & 7;
                float4 v = *(const float4*)((const float*)Aptr +
                                            (mbase + row) * 256 + kt + seg * 4);
                bf16x4 o;
                o[0] = (__bf16)v.x; o[1] = (__bf16)v.y;
                o[2] = (__bf16)v.z; o[3] = (__bf16)v.w;
                *(bf16x4*)&As[row * LSTR + seg * 4] = o;
            }
        } else {
            // 128 rows x 4 segs of 8 bf16 = 512 chunks, 1/thread
            int row = tid >> 2, seg = tid & 3;
            *(bf16x8*)&As[row * LSTR + seg * 8] =
                *(const bf16x8*)((const __bf16*)Aptr + (mbase + row) * 256 + kt + seg * 8);
        }
        // B: 256 rows x 4 segs of 8 bf16 = 1024 chunks, 2/thread
        for (int c = tid; c < 256 * 4; c += 512) {
            int row = c >> 2, seg = c & 3;
            *(bf16x8*)&Bs[row * LSTR + seg * 8] =
                *(const bf16x8*)(Bt + (long)row * 256 + kt + seg * 8);
        }
        __syncthreads();

        bf16x8 aF = *(const bf16x8*)&As[(wave * 16 + r16) * LSTR + kq * 8];
#pragma unroll
        for (int n = 0; n < 16; ++n) {
            bf16x8 bF = *(const bf16x8*)&Bs[(n * 16 + r16) * LSTR + kq * 8];
            acc[n] = __builtin_amdgcn_mfma_f32_16x16x32_bf16(aF, bF, acc[n], 0, 0, 0);
        }
    }

    long row0 = mbase + wave * 16 + kq * 4;
#pragma unroll
    for (int n = 0; n < 16; ++n) {
        int col = n * 16 + r16;
        float bz = bias[col];
#pragma unroll
        for (int r = 0; r < 4; ++r) {
            float v = acc[n][r] + bz;
            if (OUT_BF16) ((__bf16*)Out)[(row0 + r) * 256 + col] = (__bf16)v;
            else          ((float*) Out)[(row0 + r) * 256 + col] = v;
        }
    }
}

// ---------------- sampling: softmax + bilinear gather + point reduction ------
// 2 queries per wave (32 lanes each). lane&31 -> (head h = l>>2, group dg = l&3),
// each lane produces 8 channels c = h*32 + dg*8 .. +7 via 16-B gathers.
__global__ __launch_bounds__(256) void sample_kernel(
    const float* __restrict__ P,          // [MTOT][96]: 64 offsets | 32 attn logits
    const float* __restrict__ refp,       // [MTOT][2]
    const __bf16* __restrict__ vproj,     // [B][HW][256], pixel-major channels
    __bf16* __restrict__ out_mid)         // [MTOT][256]
{
    const int tid = threadIdx.x;
    const int q   = blockIdx.x * 8 + (tid >> 5);
    const int l   = tid & 31;
    const int h = l >> 2, dg = l & 3;
    const int b = q >> 14;                 // NQ = 16384
    const float* Pr = P + (long)q * 96;
    const float rx = refp[(long)q * 2 + 0];
    const float ry = refp[(long)q * 2 + 1];

    // softmax over this head's 4 logits (redundant across the 4 lanes of a head)
    float lg0 = Pr[64 + h * 4 + 0], lg1 = Pr[64 + h * 4 + 1];
    float lg2 = Pr[64 + h * 4 + 2], lg3 = Pr[64 + h * 4 + 3];
    float mx = fmaxf(fmaxf(lg0, lg1), fmaxf(lg2, lg3));
    float e0 = __expf(lg0 - mx), e1 = __expf(lg1 - mx);
    float e2 = __expf(lg2 - mx), e3 = __expf(lg3 - mx);
    float inv = 1.f / (e0 + e1 + e2 + e3);
    float at[4] = {e0 * inv, e1 * inv, e2 * inv, e3 * inv};

    const __bf16* vb = vproj + (((long)b << 14)) * 256 + h * 32 + dg * 8;
    float a[8];
#pragma unroll
    for (int i = 0; i < 8; ++i) a[i] = 0.f;

#pragma unroll
    for (int p = 0; p < 4; ++p) {
        float ox = Pr[h * 8 + p * 2 + 0] * (0.1f / 128.f);
        float oy = Pr[h * 8 + p * 2 + 1] * (0.1f / 128.f);
        float lx = fminf(fmaxf(rx + ox, 0.f), 1.f);
        float ly = fminf(fmaxf(ry + oy, 0.f), 1.f);
        float ixf = lx * 128.f - 0.5f;
        float iyf = ly * 128.f - 0.5f;
        float x0f = floorf(ixf), y0f = floorf(iyf);
        float wx = ixf - x0f,  wy = iyf - y0f;
        int x0 = (int)x0f, y0 = (int)y0f;
        float attn = at[p];
#pragma unroll
        for (int cy = 0; cy < 2; ++cy) {
#pragma unroll
            for (int cx = 0; cx < 2; ++cx) {
                int xc = x0 + cx, yc = y0 + cy;
                if (xc < 0 || xc > 127 || yc < 0 || yc > 127) continue;  // zero-pad
                float w = (cx ? wx : 1.f - wx) * (cy ? wy : 1.f - wy) * attn;
                const uint4 v = *(const uint4*)(vb + (yc * 128 + xc) * 256);
#pragma unroll
                for (int j = 0; j < 4; ++j) {
                    unsigned u = (&v.x)[j];
                    float flo = __uint_as_float(u << 16);
                    float fhi = __uint_as_float(u & 0xFFFF0000u);
                    a[2 * j + 0] += w * flo;
                    a[2 * j + 1] += w * fhi;
                }
            }
        }
    }
    bf16x8 o;
#pragma unroll
    for (int i = 0; i < 8; ++i) o[i] = (__bf16)a[i];
    *(bf16x8*)(out_mid + (long)q * 256 + h * 32 + dg * 8) = o;
}

extern "C" void kernel_launch(void* const* d_in, const int* in_sizes, int n_in,
                              void* d_out, int out_size, void* d_ws, size_t ws_size,
                              hipStream_t stream)
{
    const float* query  = (const float*)d_in[0];
    const float* refp   = (const float*)d_in[1];
    const float* value  = (const float*)d_in[2];
    const float* W_off  = (const float*)d_in[3];
    const float* b_off  = (const float*)d_in[4];
    const float* W_attn = (const float*)d_in[5];
    const float* b_attn = (const float*)d_in[6];
    const float* W_v    = (const float*)d_in[7];
    const float* b_v    = (const float*)d_in[8];
    const float* W_out  = (const float*)d_in[9];
    const float* b_out  = (const float*)d_in[10];

    // workspace carve (~88.3 MB total)
    char* w = (char*)d_ws;
    float*  P       = (float*)w;   w += (size_t)MTOT * 96 * 4;    // 24 MB
    __bf16* vproj   = (__bf16*)w;  w += (size_t)MTOT * 256 * 2;   // 32 MB
    __bf16* out_mid = (__bf16*)w;  w += (size_t)MTOT * 256 * 2;   // 32 MB
    __bf16* W1t     = (__bf16*)w;  w += 96 * 256 * 2;
    __bf16* Wvt     = (__bf16*)w;  w += 256 * 256 * 2;
    __bf16* Wot     = (__bf16*)w;  w += 256 * 256 * 2;
    float*  bias1   = (float*)w;   w += 96 * 4;

    prep_weights<<<120, 256, 0, stream>>>(W_off, W_attn, b_off, b_attn,
                                          W_v, W_out, W1t, Wvt, Wot, bias1);
    // P = query @ [W_off|W_attn] + bias1
    gemm96<<<MTOT / 128, 256, 0, stream>>>(query, W1t, bias1, P);
    // vproj = value @ W_v + b_v   (bf16, pixel-major), A read once
    gemm256<true, true><<<MTOT / 128, 512, 0, stream>>>(value, Wvt, b_v, vproj);
    // bilinear sampling + attention reduction
    sample_kernel<<<MTOT / 8, 256, 0, stream>>>(P, refp, vproj, out_mid);
    // out = out_mid @ W_out + b_out  (fp32), A read once
    gemm256<false, false><<<MTOT / 128, 512, 0, stream>>>(out_mid, Wot, b_out, d_out);
}

// Round 3
// 109.273 us; speedup vs baseline: 1.4318x; 1.2344x over previous
//
#include <hip/hip_runtime.h>
#include <hip/hip_bf16.h>

// Problem constants (fixed by the reference)
#define HWPIX  16384      // 128*128
#define MTOT   65536      // B*NQ == B*H*W

typedef __attribute__((ext_vector_type(8))) __bf16 bf16x8;
typedef __attribute__((ext_vector_type(4))) __bf16 bf16x4;
typedef __attribute__((ext_vector_type(4))) float  f32x4;

// async global->LDS, 16B per lane; LDS dest must be linear in lane index
#define GLOAD_LDS16(gsrc, ldst)                                                  \
    __builtin_amdgcn_global_load_lds(                                            \
        (const __attribute__((address_space(1))) void*)(gsrc),                   \
        (__attribute__((address_space(3))) void*)(ldst), 16, 0, 0)

// ---------------- weight prep: transpose to [N][K] + bf16 ----------------
__global__ void prep_weights(const float* __restrict__ Woff,
                             const float* __restrict__ Wattn,
                             const float* __restrict__ boff,
                             const float* __restrict__ battn,
                             const float* __restrict__ Wv,
                             const float* __restrict__ Wout,
                             __bf16* __restrict__ W1t,
                             __bf16* __restrict__ Wvt,
                             __bf16* __restrict__ Wot,
                             float* __restrict__ bias1)
{
    int tid = blockIdx.x * blockDim.x + threadIdx.x;
    int stride = gridDim.x * blockDim.x;
    for (int i = tid; i < 96 * 256; i += stride) {
        int n = i >> 8, k = i & 255;
        float v = (n < 64) ? Woff[k * 64 + n] : Wattn[k * 32 + (n - 64)];
        W1t[i] = (__bf16)v;
    }
    for (int i = tid; i < 256 * 256; i += stride) {
        int n = i >> 8, k = i & 255;
        Wvt[i] = (__bf16)Wv[k * 256 + n];
        Wot[i] = (__bf16)Wout[k * 256 + n];
    }
    for (int i = tid; i < 96; i += stride)
        bias1[i] = (i < 64) ? boff[i] : battn[i - 64];
}

// ---------------- GEMM1: P[M,96](bf16) = A[M,256](f32) @ Bt[96,256]^T + bias --
__global__ __launch_bounds__(256) void gemm96(
    const float* __restrict__ A,
    const __bf16* __restrict__ Bt,
    const float* __restrict__ bias,
    __bf16* __restrict__ P)
{
    constexpr int BM = 128, BN = 96, NF = 6;
    __shared__ __bf16 As[BM * 32];      // linear [row][32]
    __shared__ __bf16 Bs[BN * 32];

    const int tid  = threadIdx.x;
    const int wave = tid >> 6, lane = tid & 63;
    const int r16  = lane & 15, kq = lane >> 4;
    const long mbase = (long)blockIdx.x * BM;

    f32x4 acc[2][NF];
#pragma unroll
    for (int m = 0; m < 2; ++m)
#pragma unroll
        for (int n = 0; n < NF; ++n) acc[m][n] = f32x4{0.f, 0.f, 0.f, 0.f};

    for (int kt = 0; kt < 256; kt += 32) {
        __syncthreads();
        // A: fp32 -> bf16 convert during staging (512 chunks of 8 elems)
        for (int c = tid; c < BM * 4; c += 256) {
            int row = c >> 2, seg = c & 3;
            const float4* src = (const float4*)(A + (mbase + row) * 256 + kt + seg * 8);
            float4 v0 = src[0], v1 = src[1];
            bf16x8 o;
            o[0] = (__bf16)v0.x; o[1] = (__bf16)v0.y; o[2] = (__bf16)v0.z; o[3] = (__bf16)v0.w;
            o[4] = (__bf16)v1.x; o[5] = (__bf16)v1.y; o[6] = (__bf16)v1.z; o[7] = (__bf16)v1.w;
            *(bf16x8*)&As[c * 8] = o;
        }
        // B: async direct to LDS
        for (int c = tid; c < BN * 4; c += 256)
            GLOAD_LDS16(Bt + (long)(c >> 2) * 256 + kt + (c & 3) * 8, &Bs[c * 8]);
        __syncthreads();

        bf16x8 aF0 = *(const bf16x8*)&As[(wave * 32 + r16) * 32 + kq * 8];
        bf16x8 aF1 = *(const bf16x8*)&As[(wave * 32 + 16 + r16) * 32 + kq * 8];
#pragma unroll
        for (int n = 0; n < NF; ++n) {
            bf16x8 bF = *(const bf16x8*)&Bs[(n * 16 + r16) * 32 + kq * 8];
            acc[0][n] = __builtin_amdgcn_mfma_f32_16x16x32_bf16(aF0, bF, acc[0][n], 0, 0, 0);
            acc[1][n] = __builtin_amdgcn_mfma_f32_16x16x32_bf16(aF1, bF, acc[1][n], 0, 0, 0);
        }
    }

#pragma unroll
    for (int m = 0; m < 2; ++m) {
        long row0 = mbase + wave * 32 + m * 16 + kq * 4;
#pragma unroll
        for (int n = 0; n < NF; ++n) {
            int col = n * 16 + r16;
            float bz = bias[col];
#pragma unroll
            for (int r = 0; r < 4; ++r)
                P[(row0 + r) * 96 + col] = (__bf16)(acc[m][n][r] + bz);
        }
    }
}

// ---------------- GEMM256: Out[M,256] = A[M,256] @ Bt[256,256]^T + bias ----
// 512 threads / 8 waves; wave w owns rows w*16..+16, all 256 cols. A read once.
template<bool A_F32, bool OUT_BF16>
__global__ __launch_bounds__(512) void gemm256(
    const void* __restrict__ Aptr,
    const __bf16* __restrict__ Bt,
    const float* __restrict__ bias,
    void* __restrict__ Out)
{
    constexpr int BM = 128;
    __shared__ __bf16 As[BM * 32];      // 8 KB, linear
    __shared__ __bf16 Bs[256 * 32];     // 16 KB, linear

    const int tid  = threadIdx.x;
    const int wave = tid >> 6, lane = tid & 63;
    const int r16  = lane & 15, kq = lane >> 4;
    const long mbase = (long)blockIdx.x * BM;

    f32x4 acc[16];
#pragma unroll
    for (int n = 0; n < 16; ++n) acc[n] = f32x4{0.f, 0.f, 0.f, 0.f};

    for (int kt = 0; kt < 256; kt += 32) {
        __syncthreads();
        if (A_F32) {
            // 128 rows x 8 segs of 4 floats; conversion path
            for (int c = tid; c < BM * 8; c += 512) {
                float4 v = *(const float4*)((const float*)Aptr +
                                            (mbase + (c >> 3)) * 256 + kt + (c & 7) * 4);
                bf16x4 o;
                o[0] = (__bf16)v.x; o[1] = (__bf16)v.y;
                o[2] = (__bf16)v.z; o[3] = (__bf16)v.w;
                *(bf16x4*)&As[c * 4] = o;
            }
        } else {
            // bf16 A: async direct to LDS (512 chunks, 1/thread)
            int c = tid;
            GLOAD_LDS16((const __bf16*)Aptr + (mbase + (c >> 2)) * 256 + kt + (c & 3) * 8,
                        &As[c * 8]);
        }
        for (int c = tid; c < 256 * 4; c += 512)
            GLOAD_LDS16(Bt + (long)(c >> 2) * 256 + kt + (c & 3) * 8, &Bs[c * 8]);
        __syncthreads();

        bf16x8 aF = *(const bf16x8*)&As[(wave * 16 + r16) * 32 + kq * 8];
#pragma unroll
        for (int n = 0; n < 16; ++n) {
            bf16x8 bF = *(const bf16x8*)&Bs[(n * 16 + r16) * 32 + kq * 8];
            acc[n] = __builtin_amdgcn_mfma_f32_16x16x32_bf16(aF, bF, acc[n], 0, 0, 0);
        }
    }

    long row0 = mbase + wave * 16 + kq * 4;
#pragma unroll
    for (int n = 0; n < 16; ++n) {
        int col = n * 16 + r16;
        float bz = bias[col];
#pragma unroll
        for (int r = 0; r < 4; ++r) {
            float v = acc[n][r] + bz;
            if (OUT_BF16) ((__bf16*)Out)[(row0 + r) * 256 + col] = (__bf16)v;
            else          ((float*) Out)[(row0 + r) * 256 + col] = v;
        }
    }
}

// ---------------- sampling: softmax + bilinear gather + point reduction ------
// 2 queries per wave. lane&31 -> (head h = l>>2, group dg = l&3); 8 ch/lane.
// Gathers issued 8-deep (explicit uint4 array) for memory-level parallelism.
__global__ __launch_bounds__(256) void sample_kernel(
    const __bf16* __restrict__ P,         // [MTOT][96] bf16: 64 offsets | 32 logits
    const float* __restrict__ refp,       // [MTOT][2]
    const __bf16* __restrict__ vproj,     // [B][HW][256], pixel-major channels
    __bf16* __restrict__ out_mid)         // [MTOT][256]
{
    const int tid = threadIdx.x;
    const int q   = blockIdx.x * 8 + (tid >> 5);
    const int l   = tid & 31;
    const int h = l >> 2, dg = l & 3;
    const int b = q >> 14;                 // NQ = 16384
    const __bf16* Pr = P + (long)q * 96;
    const float rx = refp[(long)q * 2 + 0];
    const float ry = refp[(long)q * 2 + 1];

    // my head's 8 offsets + 4 logits, two vector loads
    bf16x8 off8 = *(const bf16x8*)(Pr + h * 8);
    bf16x4 lg4  = *(const bf16x4*)(Pr + 64 + h * 4);
    float lg0 = (float)lg4[0], lg1 = (float)lg4[1];
    float lg2 = (float)lg4[2], lg3 = (float)lg4[3];
    float mx = fmaxf(fmaxf(lg0, lg1), fmaxf(lg2, lg3));
    float e0 = __expf(lg0 - mx), e1 = __expf(lg1 - mx);
    float e2 = __expf(lg2 - mx), e3 = __expf(lg3 - mx);
    float inv = 1.f / (e0 + e1 + e2 + e3);
    float at[4] = {e0 * inv, e1 * inv, e2 * inv, e3 * inv};

    const __bf16* vb = vproj + (((long)b << 14)) * 256 + h * 32 + dg * 8;
    float a[8];
#pragma unroll
    for (int i = 0; i < 8; ++i) a[i] = 0.f;

#pragma unroll
    for (int c2 = 0; c2 < 2; ++c2) {       // two points per chunk -> 8 gathers
        int   idx[8];
        float wt[8];
#pragma unroll
        for (int pp = 0; pp < 2; ++pp) {
            int p = c2 * 2 + pp;
            float ox = (float)off8[2 * p + 0] * (0.1f / 128.f);
            float oy = (float)off8[2 * p + 1] * (0.1f / 128.f);
            float lx = fminf(fmaxf(rx + ox, 0.f), 1.f);
            float ly = fminf(fmaxf(ry + oy, 0.f), 1.f);
            float ixf = lx * 128.f - 0.5f;
            float iyf = ly * 128.f - 0.5f;
            float x0f = floorf(ixf), y0f = floorf(iyf);
            float wx = ixf - x0f,  wy = iyf - y0f;
            int x0 = (int)x0f, y0 = (int)y0f;
            float attn = at[p];
#pragma unroll
            for (int cy = 0; cy < 2; ++cy) {
#pragma unroll
                for (int cx = 0; cx < 2; ++cx) {
                    int xc = x0 + cx, yc = y0 + cy;
                    float inb = (xc >= 0 && xc < 128 && yc >= 0 && yc < 128) ? 1.f : 0.f;
                    int xcc = min(max(xc, 0), 127), ycc = min(max(yc, 0), 127);
                    idx[pp * 4 + cy * 2 + cx] = (ycc * 128 + xcc) * 256;
                    wt[pp * 4 + cy * 2 + cx] =
                        (cx ? wx : 1.f - wx) * (cy ? wy : 1.f - wy) * attn * inb;
                }
            }
        }
        uint4 v[8];
#pragma unroll
        for (int i = 0; i < 8; ++i)
            v[i] = *(const uint4*)(vb + idx[i]);     // 8 loads in flight
#pragma unroll
        for (int i = 0; i < 8; ++i) {
            float w = wt[i];
#pragma unroll
            for (int j = 0; j < 4; ++j) {
                unsigned u = (&v[i].x)[j];
                a[2 * j + 0] += w * __uint_as_float(u << 16);
                a[2 * j + 1] += w * __uint_as_float(u & 0xFFFF0000u);
            }
        }
    }
    bf16x8 o;
#pragma unroll
    for (int i = 0; i < 8; ++i) o[i] = (__bf16)a[i];
    *(bf16x8*)(out_mid + (long)q * 256 + h * 32 + dg * 8) = o;
}

extern "C" void kernel_launch(void* const* d_in, const int* in_sizes, int n_in,
                              void* d_out, int out_size, void* d_ws, size_t ws_size,
                              hipStream_t stream)
{
    const float* query  = (const float*)d_in[0];
    const float* refp   = (const float*)d_in[1];
    const float* value  = (const float*)d_in[2];
    const float* W_off  = (const float*)d_in[3];
    const float* b_off  = (const float*)d_in[4];
    const float* W_attn = (const float*)d_in[5];
    const float* b_attn = (const float*)d_in[6];
    const float* W_v    = (const float*)d_in[7];
    const float* b_v    = (const float*)d_in[8];
    const float* W_out  = (const float*)d_in[9];
    const float* b_out  = (const float*)d_in[10];

    // workspace carve (~76.5 MB total)
    char* w = (char*)d_ws;
    __bf16* P       = (__bf16*)w;  w += (size_t)MTOT * 96 * 2;    // 12 MB
    __bf16* vproj   = (__bf16*)w;  w += (size_t)MTOT * 256 * 2;   // 32 MB
    __bf16* out_mid = (__bf16*)w;  w += (size_t)MTOT * 256 * 2;   // 32 MB
    __bf16* W1t     = (__bf16*)w;  w += 96 * 256 * 2;
    __bf16* Wvt     = (__bf16*)w;  w += 256 * 256 * 2;
    __bf16* Wot     = (__bf16*)w;  w += 256 * 256 * 2;
    float*  bias1   = (float*)w;   w += 96 * 4;

    prep_weights<<<120, 256, 0, stream>>>(W_off, W_attn, b_off, b_attn,
                                          W_v, W_out, W1t, Wvt, Wot, bias1);
    gemm96<<<MTOT / 128, 256, 0, stream>>>(query, W1t, bias1, P);
    gemm256<true, true><<<MTOT / 128, 512, 0, stream>>>(value, Wvt, b_v, vproj);
    sample_kernel<<<MTOT / 8, 256, 0, stream>>>(P, refp, vproj, out_mid);
    gemm256<false, false><<<MTOT / 128, 512, 0, stream>>>(out_mid, Wot, b_out, d_out);
}

// Round 4
// 88.390 us; speedup vs baseline: 1.7701x; 1.2363x over previous
//
#include <hip/hip_runtime.h>
#include <hip/hip_bf16.h>

#define HWPIX  16384      // 128*128
#define MTOT   65536      // B*NQ == B*H*W

typedef __attribute__((ext_vector_type(8))) __bf16 bf16x8;
typedef __attribute__((ext_vector_type(4))) __bf16 bf16x4;
typedef __attribute__((ext_vector_type(4))) float  f32x4;

// async global->LDS, 16B per lane; LDS dest must be linear in lane index
#define GLOAD_LDS16(gsrc, ldst)                                                  \
    __builtin_amdgcn_global_load_lds(                                            \
        (const __attribute__((address_space(1))) void*)(gsrc),                   \
        (__attribute__((address_space(3))) void*)(ldst), 16, 0, 0)

// ---------------- weight prep: transpose to [N][K] + bf16 ----------------
__global__ void prep_weights(const float* __restrict__ Woff,
                             const float* __restrict__ Wattn,
                             const float* __restrict__ boff,
                             const float* __restrict__ battn,
                             const float* __restrict__ Wv,
                             const float* __restrict__ Wout,
                             __bf16* __restrict__ W1t,
                             __bf16* __restrict__ Wvt,
                             __bf16* __restrict__ Wot,
                             float* __restrict__ bias1)
{
    int tid = blockIdx.x * blockDim.x + threadIdx.x;
    int stride = gridDim.x * blockDim.x;
    for (int i = tid; i < 96 * 256; i += stride) {
        int n = i >> 8, k = i & 255;
        float v = (n < 64) ? Woff[k * 64 + n] : Wattn[k * 32 + (n - 64)];
        W1t[i] = (__bf16)v;
    }
    for (int i = tid; i < 256 * 256; i += stride) {
        int n = i >> 8, k = i & 255;
        Wvt[i] = (__bf16)Wv[k * 256 + n];
        Wot[i] = (__bf16)Wout[k * 256 + n];
    }
    for (int i = tid; i < 96; i += stride)
        bias1[i] = (i < 64) ? boff[i] : battn[i - 64];
}

// -------- GEMM1: P[M,96](bf16) = query[M,256](f32) @ W1t[96,256]^T + bias ----
// 256 thr / 4 waves, BM=128. 2-phase: issue loads(t+1) before compute(t),
// convert+ds_write(t+1) after compute(t). Double-buffered LDS.
__global__ __launch_bounds__(256, 4) void gemm96(
    const float* __restrict__ A,
    const __bf16* __restrict__ Bt,
    const float* __restrict__ bias,
    __bf16* __restrict__ P)
{
    constexpr int NF = 6;
    __shared__ __bf16 As[2][128 * 32];   // 2 x 8 KB
    __shared__ __bf16 Bs[2][96 * 32];    // 2 x 6 KB

    const int tid  = threadIdx.x;
    const int wave = tid >> 6, lane = tid & 63;
    const int r16  = lane & 15, kq = lane >> 4;
    const long mbase = (long)blockIdx.x * 128;

    // A: 1024 float4 chunks / tile; 4 per thread (c = tid + k*256)
    const float* ap0 = A + (mbase + ((tid + 0 * 256) >> 3)) * 256 + (tid & 7) * 4;
    const float* ap1 = A + (mbase + ((tid + 1 * 256) >> 3)) * 256 + (tid & 7) * 4;
    const float* ap2 = A + (mbase + ((tid + 2 * 256) >> 3)) * 256 + (tid & 7) * 4;
    const float* ap3 = A + (mbase + ((tid + 3 * 256) >> 3)) * 256 + (tid & 7) * 4;
    // B: 384 chunks / tile; chunk tid and (tid+256 if tid<128)
    const __bf16* bp0 = Bt + (long)(tid >> 2) * 256 + (tid & 3) * 8;
    const __bf16* bp1 = Bt + (long)((tid + 256) >> 2) * 256 + (tid & 3) * 8;

    f32x4 acc[2][NF];
#pragma unroll
    for (int m = 0; m < 2; ++m)
#pragma unroll
        for (int n = 0; n < NF; ++n) acc[m][n] = f32x4{0.f, 0.f, 0.f, 0.f};

    // prologue: tile 0
    float4 ra0 = *(const float4*)ap0, ra1 = *(const float4*)ap1;
    float4 ra2 = *(const float4*)ap2, ra3 = *(const float4*)ap3;
    GLOAD_LDS16(bp0, &Bs[0][tid * 8]);
    if (tid < 128) GLOAD_LDS16(bp1, &Bs[0][(tid + 256) * 8]);
#define CW96(buf)                                                                 \
    {                                                                             \
        bf16x4 o;                                                                 \
        o[0] = (__bf16)ra0.x; o[1] = (__bf16)ra0.y; o[2] = (__bf16)ra0.z; o[3] = (__bf16)ra0.w; \
        *(bf16x4*)&As[buf][(tid + 0 * 256) * 4] = o;                              \
        o[0] = (__bf16)ra1.x; o[1] = (__bf16)ra1.y; o[2] = (__bf16)ra1.z; o[3] = (__bf16)ra1.w; \
        *(bf16x4*)&As[buf][(tid + 1 * 256) * 4] = o;                              \
        o[0] = (__bf16)ra2.x; o[1] = (__bf16)ra2.y; o[2] = (__bf16)ra2.z; o[3] = (__bf16)ra2.w; \
        *(bf16x4*)&As[buf][(tid + 2 * 256) * 4] = o;                              \
        o[0] = (__bf16)ra3.x; o[1] = (__bf16)ra3.y; o[2] = (__bf16)ra3.z; o[3] = (__bf16)ra3.w; \
        *(bf16x4*)&As[buf][(tid + 3 * 256) * 4] = o;                              \
    }
    CW96(0);
    __syncthreads();

    for (int t = 0; t < 8; ++t) {
        const int cur = t & 1, nxt = cur ^ 1;
        if (t < 7) {
            const int kt = (t + 1) * 32;
            ra0 = *(const float4*)(ap0 + kt);
            ra1 = *(const float4*)(ap1 + kt);
            ra2 = *(const float4*)(ap2 + kt);
            ra3 = *(const float4*)(ap3 + kt);
            GLOAD_LDS16(bp0 + kt, &Bs[nxt][tid * 8]);
            if (tid < 128) GLOAD_LDS16(bp1 + kt, &Bs[nxt][(tid + 256) * 8]);
        }
        bf16x8 aF0 = *(const bf16x8*)&As[cur][(wave * 32 + r16) * 32 + kq * 8];
        bf16x8 aF1 = *(const bf16x8*)&As[cur][(wave * 32 + 16 + r16) * 32 + kq * 8];
#pragma unroll
        for (int n = 0; n < NF; ++n) {
            bf16x8 bF = *(const bf16x8*)&Bs[cur][(n * 16 + r16) * 32 + kq * 8];
            acc[0][n] = __builtin_amdgcn_mfma_f32_16x16x32_bf16(aF0, bF, acc[0][n], 0, 0, 0);
            acc[1][n] = __builtin_amdgcn_mfma_f32_16x16x32_bf16(aF1, bF, acc[1][n], 0, 0, 0);
        }
        if (t < 7) CW96(nxt);
        __syncthreads();
    }

#pragma unroll
    for (int m = 0; m < 2; ++m) {
        long row0 = mbase + wave * 32 + m * 16 + kq * 4;
#pragma unroll
        for (int n = 0; n < NF; ++n) {
            int col = n * 16 + r16;
            float bz = bias[col];
#pragma unroll
            for (int r = 0; r < 4; ++r)
                P[(row0 + r) * 96 + col] = (__bf16)(acc[m][n][r] + bz);
        }
    }
}

// -------- GEMM2: vproj[M,256](bf16) = value[M,256](f32) @ Wvt^T + b_v --------
// 512 thr / 8 waves, BM=128, 2-phase double-buffered (same schedule as gemm96).
__global__ __launch_bounds__(512, 4) void gemm256_v(
    const float* __restrict__ A,
    const __bf16* __restrict__ Bt,
    const float* __restrict__ bias,
    __bf16* __restrict__ Out)
{
    __shared__ __bf16 As[2][128 * 32];   // 2 x 8 KB
    __shared__ __bf16 Bs[2][256 * 32];   // 2 x 16 KB

    const int tid  = threadIdx.x;
    const int wave = tid >> 6, lane = tid & 63;
    const int r16  = lane & 15, kq = lane >> 4;
    const long mbase = (long)blockIdx.x * 128;

    // A: 1024 float4 chunks / tile; 2 per thread
    const float* ap0 = A + (mbase + (tid >> 3)) * 256 + (tid & 7) * 4;
    const float* ap1 = ap0 + 64 * 256;
    // B: 1024 chunks / tile; 2 per thread
    const __bf16* bp0 = Bt + (long)(tid >> 2) * 256 + (tid & 3) * 8;
    const __bf16* bp1 = bp0 + 128 * 256;

    f32x4 acc[16];
#pragma unroll
    for (int n = 0; n < 16; ++n) acc[n] = f32x4{0.f, 0.f, 0.f, 0.f};

    float4 ra0 = *(const float4*)ap0, ra1 = *(const float4*)ap1;
    GLOAD_LDS16(bp0, &Bs[0][tid * 8]);
    GLOAD_LDS16(bp1, &Bs[0][(tid + 512) * 8]);
#define CW256(buf)                                                                \
    {                                                                             \
        bf16x4 o;                                                                 \
        o[0] = (__bf16)ra0.x; o[1] = (__bf16)ra0.y; o[2] = (__bf16)ra0.z; o[3] = (__bf16)ra0.w; \
        *(bf16x4*)&As[buf][tid * 4] = o;                                          \
        o[0] = (__bf16)ra1.x; o[1] = (__bf16)ra1.y; o[2] = (__bf16)ra1.z; o[3] = (__bf16)ra1.w; \
        *(bf16x4*)&As[buf][(tid + 512) * 4] = o;                                  \
    }
    CW256(0);
    __syncthreads();

    for (int t = 0; t < 8; ++t) {
        const int cur = t & 1, nxt = cur ^ 1;
        if (t < 7) {
            const int kt = (t + 1) * 32;
            ra0 = *(const float4*)(ap0 + kt);
            ra1 = *(const float4*)(ap1 + kt);
            GLOAD_LDS16(bp0 + kt, &Bs[nxt][tid * 8]);
            GLOAD_LDS16(bp1 + kt, &Bs[nxt][(tid + 512) * 8]);
        }
        bf16x8 aF = *(const bf16x8*)&As[cur][(wave * 16 + r16) * 32 + kq * 8];
#pragma unroll
        for (int n = 0; n < 16; ++n) {
            bf16x8 bF = *(const bf16x8*)&Bs[cur][(n * 16 + r16) * 32 + kq * 8];
            acc[n] = __builtin_amdgcn_mfma_f32_16x16x32_bf16(aF, bF, acc[n], 0, 0, 0);
        }
        if (t < 7) CW256(nxt);
        __syncthreads();
    }

    long row0 = mbase + wave * 16 + kq * 4;
#pragma unroll
    for (int n = 0; n < 16; ++n) {
        int col = n * 16 + r16;
        float bz = bias[col];
#pragma unroll
        for (int r = 0; r < 4; ++r)
            Out[(row0 + r) * 256 + col] = (__bf16)(acc[n][r] + bz);
    }
}

// -------- fused sampler + GEMM3: d_out[M,256](f32) ---------------------------
// Per block: 128 queries. Phase 1: sample into 64KB XOR-swizzled LDS A-tile.
// Phase 2: MFMA vs Wot (staged per K-step via global_load_lds), + b_out.
__global__ __launch_bounds__(512, 4) void sample_out_fused(
    const __bf16* __restrict__ P,         // [MTOT][96] bf16
    const float* __restrict__ refp,       // [MTOT][2]
    const __bf16* __restrict__ vproj,     // [B][HW][256]
    const __bf16* __restrict__ Wot,       // [256][256] bf16 pre-transposed
    const float* __restrict__ bias,
    float* __restrict__ Out)
{
    __shared__ __bf16 As[128 * 256];   // 64 KB, rows XOR-swizzled by (row&7)<<4
    __shared__ __bf16 Bs[256 * 32];    // 16 KB

    const int tid = threadIdx.x;
    const int bid = blockIdx.x;
    const int swz = (bid & 7) * 64 + (bid >> 3);      // XCD-aware, 512%8==0
    const long qbase = (long)swz * 128;

    // ---------- phase 1: sampling (16 groups x 32 lanes; 8 queries each) ----
    {
        const int g = tid >> 5, l = tid & 31;
        const int h = l >> 2, dg = l & 3;
        const int colbyte = h * 64 + dg * 16;
        for (int i = 0; i < 8; ++i) {
            const int  ql = g * 8 + i;
            const long q  = qbase + ql;
            const __bf16* Pr = P + q * 96;
            const float rx = refp[q * 2 + 0];
            const float ry = refp[q * 2 + 1];
            bf16x8 off8 = *(const bf16x8*)(Pr + h * 8);
            bf16x4 lg4  = *(const bf16x4*)(Pr + 64 + h * 4);
            float lg0 = (float)lg4[0], lg1 = (float)lg4[1];
            float lg2 = (float)lg4[2], lg3 = (float)lg4[3];
            float mx = fmaxf(fmaxf(lg0, lg1), fmaxf(lg2, lg3));
            float e0 = __expf(lg0 - mx), e1 = __expf(lg1 - mx);
            float e2 = __expf(lg2 - mx), e3 = __expf(lg3 - mx);
            float inv = 1.f / (e0 + e1 + e2 + e3);
            float at[4] = {e0 * inv, e1 * inv, e2 * inv, e3 * inv};

            const __bf16* vb = vproj + ((q >> 14) << 14) * 256 + h * 32 + dg * 8;
            float a[8];
#pragma unroll
            for (int j = 0; j < 8; ++j) a[j] = 0.f;

#pragma unroll
            for (int c2 = 0; c2 < 2; ++c2) {
                int   idx[8];
                float wt[8];
#pragma unroll
                for (int pp = 0; pp < 2; ++pp) {
                    int p = c2 * 2 + pp;
                    float ox = (float)off8[2 * p + 0] * (0.1f / 128.f);
                    float oy = (float)off8[2 * p + 1] * (0.1f / 128.f);
                    float lx = fminf(fmaxf(rx + ox, 0.f), 1.f);
                    float ly = fminf(fmaxf(ry + oy, 0.f), 1.f);
                    float ixf = lx * 128.f - 0.5f;
                    float iyf = ly * 128.f - 0.5f;
                    float x0f = floorf(ixf), y0f = floorf(iyf);
                    float wx = ixf - x0f,  wy = iyf - y0f;
                    int x0 = (int)x0f, y0 = (int)y0f;
                    float attn = at[p];
#pragma unroll
                    for (int cy = 0; cy < 2; ++cy)
#pragma unroll
                        for (int cx = 0; cx < 2; ++cx) {
                            int xc = x0 + cx, yc = y0 + cy;
                            float inb = (xc >= 0 && xc < 128 && yc >= 0 && yc < 128) ? 1.f : 0.f;
                            int xcc = min(max(xc, 0), 127), ycc = min(max(yc, 0), 127);
                            idx[pp * 4 + cy * 2 + cx] = (ycc * 128 + xcc) * 256;
                            wt[pp * 4 + cy * 2 + cx] =
                                (cx ? wx : 1.f - wx) * (cy ? wy : 1.f - wy) * attn * inb;
                        }
                }
                uint4 v[8];
#pragma unroll
                for (int j = 0; j < 8; ++j)
                    v[j] = *(const uint4*)(vb + idx[j]);   // 8 loads in flight
#pragma unroll
                for (int j = 0; j < 8; ++j) {
                    float w = wt[j];
#pragma unroll
                    for (int k = 0; k < 4; ++k) {
                        unsigned u = (&v[j].x)[k];
                        a[2 * k + 0] += w * __uint_as_float(u << 16);
                        a[2 * k + 1] += w * __uint_as_float(u & 0xFFFF0000u);
                    }
                }
            }
            bf16x8 o;
#pragma unroll
            for (int j = 0; j < 8; ++j) o[j] = (__bf16)a[j];
            int byte = ql * 512 + (colbyte ^ ((ql & 7) << 4));
            *(bf16x8*)((char*)As + byte) = o;
        }
    }

    // ---------- phase 2: GEMM vs Wot ----------
    const int wave = tid >> 6, lane = tid & 63;
    const int r16  = lane & 15, kq = lane >> 4;
    const int arow = wave * 16 + r16;
    const int abase = arow * 512;
    const int aswz  = (arow & 7) << 4;

    f32x4 acc[16];
#pragma unroll
    for (int n = 0; n < 16; ++n) acc[n] = f32x4{0.f, 0.f, 0.f, 0.f};

    for (int kt = 0; kt < 256; kt += 32) {
        __syncthreads();   // kt=0: sampling writes done; else: prev Bs reads done
        for (int c = tid; c < 1024; c += 512)
            GLOAD_LDS16(Wot + (long)(c >> 2) * 256 + kt + (c & 3) * 8, &Bs[c * 8]);
        __syncthreads();
        bf16x8 aF = *(const bf16x8*)((char*)As + abase + ((kt * 2 + kq * 16) ^ aswz));
#pragma unroll
        for (int n = 0; n < 16; ++n) {
            bf16x8 bF = *(const bf16x8*)&Bs[(n * 16 + r16) * 32 + kq * 8];
            acc[n] = __builtin_amdgcn_mfma_f32_16x16x32_bf16(aF, bF, acc[n], 0, 0, 0);
        }
    }

    long row0 = qbase + wave * 16 + kq * 4;
#pragma unroll
    for (int n = 0; n < 16; ++n) {
        int col = n * 16 + r16;
        float bz = bias[col];
#pragma unroll
        for (int r = 0; r < 4; ++r)
            Out[(row0 + r) * 256 + col] = acc[n][r] + bz;
    }
}

extern "C" void kernel_launch(void* const* d_in, const int* in_sizes, int n_in,
                              void* d_out, int out_size, void* d_ws, size_t ws_size,
                              hipStream_t stream)
{
    const float* query  = (const float*)d_in[0];
    const float* refp   = (const float*)d_in[1];
    const float* value  = (const float*)d_in[2];
    const float* W_off  = (const float*)d_in[3];
    const float* b_off  = (const float*)d_in[4];
    const float* W_attn = (const float*)d_in[5];
    const float* b_attn = (const float*)d_in[6];
    const float* W_v    = (const float*)d_in[7];
    const float* b_v    = (const float*)d_in[8];
    const float* W_out  = (const float*)d_in[9];
    const float* b_out  = (const float*)d_in[10];

    // workspace carve (~44.5 MB total)
    char* w = (char*)d_ws;
    __bf16* P       = (__bf16*)w;  w += (size_t)MTOT * 96 * 2;    // 12 MB
    __bf16* vproj   = (__bf16*)w;  w += (size_t)MTOT * 256 * 2;   // 32 MB
    __bf16* W1t     = (__bf16*)w;  w += 96 * 256 * 2;
    __bf16* Wvt     = (__bf16*)w;  w += 256 * 256 * 2;
    __bf16* Wot     = (__bf16*)w;  w += 256 * 256 * 2;
    float*  bias1   = (float*)w;   w += 96 * 4;

    prep_weights<<<120, 256, 0, stream>>>(W_off, W_attn, b_off, b_attn,
                                          W_v, W_out, W1t, Wvt, Wot, bias1);
    gemm96<<<MTOT / 128, 256, 0, stream>>>(query, W1t, bias1, P);
    gemm256_v<<<MTOT / 128, 512, 0, stream>>>(value, Wvt, b_v, vproj);
    sample_out_fused<<<MTOT / 128, 512, 0, stream>>>(P, refp, vproj, Wot, b_out,
                                                     (float*)d_out);
}